// Round 2
// baseline (1346.735 us; speedup 1.0000x reference)
//
#include <hip/hip_runtime.h>
#include <math.h>

namespace {
constexpr int NIMG = 16;
constexpr int ICH  = 3;
constexpr int OCH  = 64;
constexpr int KS   = 7;
constexpr int H    = 512;
constexpr int W    = 512;
constexpr int TH   = 32;   // output tile height per block
constexpr int TW   = 64;   // output tile width per block
constexpr int XH   = TH + 6;
constexpr int XW   = TW + 6;
constexpr int XP   = 76;   // LDS pitch: mult of 4 (16B align); 76%32=12 -> banks 4(3ty+2tx)%32 balanced
}

__global__ __launch_bounds__(256, 4)   // cap 128 VGPR -> 4 waves/SIMD
void ridgelet_conv(const float* __restrict__ x,
                   const float* __restrict__ scales,
                   const float* __restrict__ dirs,
                   const float* __restrict__ poss,
                   float* __restrict__ out)
{
    __shared__ float xs[XH][XP];          // channel-summed input tile (padded)
    __shared__ float wl[KS * KS][OCH];    // ridgelet filter bank, [tap][oc]

    const int tid = threadIdx.x;
    const int tw0 = blockIdx.x * TW;
    const int th0 = blockIdx.y * TH;
    const int n   = blockIdx.z;

    // ---- generate filter bank into LDS (~12 exp-pairs/thread, negligible) ----
    for (int idx = tid; idx < KS * KS * OCH; idx += 256) {
        const int k  = idx >> 6;          // 0..48
        const int oc = idx & 63;
        const int kh = k / 7;
        const int kw = k - kh * 7;
        const float d  = dirs[oc];
        const float tc = ((float)(kh - 3) * cosf(d) + (float)(kw - 3) * sinf(d)
                          - poss[oc]) / scales[oc];
        const float t2 = tc * tc;
        wl[k][oc] = expf(-0.5f * t2) - 0.5f * expf(-0.125f * t2);
    }

    // ---- stage channel-summed, zero-padded input tile ----
    const float* xb = x + (size_t)n * ICH * H * W;
    for (int idx = tid; idx < XH * XW; idx += 256) {
        const int r  = idx / XW;
        const int c  = idx - r * XW;
        const int gh = th0 + r - 3;
        const int gw = tw0 + c - 3;
        float s = 0.0f;
        if ((unsigned)gh < (unsigned)H && (unsigned)gw < (unsigned)W) {
            const size_t o = (size_t)gh * W + gw;
            s = xb[o] + xb[o + (size_t)H * W] + xb[o + 2 * (size_t)H * W];
        }
        xs[r][c] = s;
    }
    __syncthreads();

    // ---- compute: thread = 1 output row x 8 output cols; 16 iters x 4 oc ----
    const int tx = tid & 7;               // w-group: cols tx*8 .. tx*8+7
    const int ty = tid >> 3;              // output row 0..31
    const int cb = tx * 8;                // local col base (halo coords)

    float* ob = out + (size_t)n * OCH * H * W
                    + (size_t)(th0 + ty) * W + (tw0 + cb);

    #pragma unroll 1
    for (int it = 0; it < 16; ++it) {
        const int ocb = it * 4;           // this iteration's 4 output channels

        float acc[4][8];                  // [oc][px]
        #pragma unroll
        for (int c = 0; c < 4; ++c)
            #pragma unroll
            for (int j = 0; j < 8; ++j)
                acc[c][j] = 0.0f;

        #pragma unroll
        for (int kh = 0; kh < KS; ++kh) {
            // 16-float input window: local cols cb .. cb+15 (need cb..cb+13)
            float win[16];
            const float* rp = &xs[ty + kh][cb];
            *(float4*)&win[0]  = *(const float4*)(rp);
            *(float4*)&win[4]  = *(const float4*)(rp + 4);
            *(float4*)&win[8]  = *(const float4*)(rp + 8);
            *(float4*)&win[12] = *(const float4*)(rp + 12);

            #pragma unroll
            for (int kw = 0; kw < KS; ++kw) {
                // 4 channels' weights: wave-uniform address -> LDS broadcast
                const float4 w4 = *(const float4*)&wl[kh * 7 + kw][ocb];
                #pragma unroll
                for (int j = 0; j < 8; ++j) {
                    const float v = win[j + kw];
                    acc[0][j] = fmaf(v, w4.x, acc[0][j]);
                    acc[1][j] = fmaf(v, w4.y, acc[1][j]);
                    acc[2][j] = fmaf(v, w4.z, acc[2][j]);
                    acc[3][j] = fmaf(v, w4.w, acc[3][j]);
                }
            }
        }

        // ---- store: 2 coalesced float4 per oc ----
        #pragma unroll
        for (int c = 0; c < 4; ++c) {
            float* p = ob + (size_t)(ocb + c) * (H * W);
            *(float4*)(p)     = make_float4(acc[c][0], acc[c][1], acc[c][2], acc[c][3]);
            *(float4*)(p + 4) = make_float4(acc[c][4], acc[c][5], acc[c][6], acc[c][7]);
        }
    }
}

extern "C" void kernel_launch(void* const* d_in, const int* in_sizes, int n_in,
                              void* d_out, int out_size, void* d_ws, size_t ws_size,
                              hipStream_t stream)
{
    const float* x  = (const float*)d_in[0];
    const float* sc = (const float*)d_in[1];
    const float* di = (const float*)d_in[2];
    const float* po = (const float*)d_in[3];
    float* outp     = (float*)d_out;

    dim3 grid(W / TW, H / TH, NIMG);   // 8 x 16 x 16 = 2048 blocks
    ridgelet_conv<<<grid, dim3(256), 0, stream>>>(x, sc, di, po, outp);
}